// Round 1
// baseline (147.424 us; speedup 1.0000x reference)
//
#include <hip/hip_runtime.h>

#define N_NODES 50000
#define N_EDGES 800000
#define IN_DIM 128
#define OUT_DIM 64

#define GROUP_ROWS 64
#define GEMM_BLOCKS 782          // ceil(50000/64)
#define CHUNK2 2048              // edges per fill block
#define FILL_BLOCKS 391          // 391*2048 >= 800000
#define ROW_CAP 64               // per-row slab capacity (mean deg 16, P(>=64) ~ 1e-17)

typedef _Float16 h2 __attribute__((ext_vector_type(2)));
typedef _Float16 h4 __attribute__((ext_vector_type(4)));
typedef _Float16 h8 __attribute__((ext_vector_type(8)));
typedef float    f4 __attribute__((ext_vector_type(4)));

#define LDK 136    // padded fp16 K-stride (multiple of 8 -> 16B-aligned b128 rows)

// ---------------------------------------------------------------------------
// D1 (fused): blocks [0,391) = fill role (latency-heavy, scheduled FIRST);
// blocks [391,1173) = MFMA fp16 GEMM per 64-row group (unchanged from the
// 124 us kernel).  Fill role now bins edges DIRECTLY into per-row slabs:
// 800K fetch-adds spread over 50000 counters (mean 16/addr) instead of
// 280K fetch-adds over 782 counters -- kills same-address L2 serialization.
// No LDS, no two-phase count/reserve, erow read once.
// ---------------------------------------------------------------------------
__global__ __launch_bounds__(256) void fused_gemm_fill(const float* __restrict__ x,
                                                       const float* __restrict__ w,
                                                       const int* __restrict__ erow,
                                                       const int* __restrict__ ecol,
                                                       const float* __restrict__ ev,
                                                       _Float16* __restrict__ support,
                                                       int* __restrict__ rowcnt,
                                                       int2* __restrict__ rowslab) {
    __shared__ char smem[GROUP_ROWS * LDK * 2 + OUT_DIM * LDK * 2];  // 34816 B
    const int tid = threadIdx.x;

    if (blockIdx.x >= FILL_BLOCKS) {
        // ---- GEMM role (blocks 391..1172, group = blockIdx-391) ----
        _Float16* xb = (_Float16*)smem;                          // [64][LDK]
        _Float16* wt = (_Float16*)(smem + GROUP_ROWS * LDK * 2); // [64][LDK], wt[n][k]

        // conflict-free wt staging (register transpose, fp16-pair stores)
        {
            const int n_s = tid >> 2;         // 0..63
            const int kp0 = tid & 3;
            #pragma unroll
            for (int it = 0; it < 16; ++it) {
                int kp = kp0 + (it << 2);     // k-pair index 0..63
                int k  = kp << 1;
                h2 hv = { (_Float16)w[(size_t)k * OUT_DIM + n_s],
                          (_Float16)w[(size_t)(k + 1) * OUT_DIM + n_s] };
                *(h2*)&wt[n_s * LDK + k] = hv;
            }
        }
        const int rowbase = (blockIdx.x - FILL_BLOCKS) * GROUP_ROWS;
        for (int i = tid; i < GROUP_ROWS * (IN_DIM / 4); i += 256) {
            int r  = i >> 5;
            int kq = i & 31;
            int row = rowbase + r;
            float4 v = (row < N_NODES)
                           ? *(const float4*)&x[(size_t)row * IN_DIM + kq * 4]
                           : make_float4(0.f, 0.f, 0.f, 0.f);
            h4 hv = { (_Float16)v.x, (_Float16)v.y, (_Float16)v.z, (_Float16)v.w };
            *(h4*)&xb[r * LDK + kq * 4] = hv;
        }
        __syncthreads();

        const int wave = tid >> 6;
        const int lane = tid & 63;
        const int mrow = lane & 15;
        const int quad = lane >> 4;
        const int m0   = wave * 16;

        f4 acc[4];
        #pragma unroll
        for (int t = 0; t < 4; ++t) acc[t] = (f4){0.f, 0.f, 0.f, 0.f};

        #pragma unroll
        for (int ks = 0; ks < 4; ++ks) {
            int kof = ks * 32 + quad * 8;
            h8 a = *(h8*)&xb[(m0 + mrow) * LDK + kof];
            #pragma unroll
            for (int t = 0; t < 4; ++t) {
                h8 b = *(h8*)&wt[(t * 16 + mrow) * LDK + kof];
                acc[t] = __builtin_amdgcn_mfma_f32_16x16x32_f16(a, b, acc[t], 0, 0, 0);
            }
        }

        #pragma unroll
        for (int t = 0; t < 4; ++t) {
            #pragma unroll
            for (int r = 0; r < 4; ++r) {
                int row = rowbase + m0 + quad * 4 + r;
                if (row < N_NODES)
                    support[(size_t)row * OUT_DIM + t * 16 + mrow] = (_Float16)acc[t][r];
            }
        }
    } else {
        // ---- fill role (blocks 0..390): per-row binning, 8 edges/thread ----
        const int o = blockIdx.x * CHUNK2 + tid * 8;
        if (o + 8 <= N_EDGES) {
            int4   ra = *(const int4*)&erow[o];
            int4   rb = *(const int4*)&erow[o + 4];
            int4   ca = *(const int4*)&ecol[o];
            int4   cb = *(const int4*)&ecol[o + 4];
            float4 va = *(const float4*)&ev[o];
            float4 vb = *(const float4*)&ev[o + 4];
            int   rr[8] = { ra.x, ra.y, ra.z, ra.w, rb.x, rb.y, rb.z, rb.w };
            int   cc[8] = { ca.x, ca.y, ca.z, ca.w, cb.x, cb.y, cb.z, cb.w };
            float vv[8] = { va.x, va.y, va.z, va.w, vb.x, vb.y, vb.z, vb.w };
            int pp[8];
            #pragma unroll
            for (int k = 0; k < 8; ++k) pp[k] = atomicAdd(&rowcnt[rr[k]], 1);
            #pragma unroll
            for (int k = 0; k < 8; ++k)
                if (pp[k] < ROW_CAP)
                    rowslab[((size_t)rr[k] << 6) + pp[k]] =
                        make_int2(cc[k], __float_as_int(vv[k]));
        } else {
            #pragma unroll
            for (int k = 0; k < 8; ++k) {
                int e = o + k;
                if (e < N_EDGES) {
                    int r = erow[e];
                    int p = atomicAdd(&rowcnt[r], 1);
                    if (p < ROW_CAP)
                        rowslab[((size_t)r << 6) + p] =
                            make_int2(ecol[e], __float_as_int(ev[e]));
                }
            }
        }
    }
}

// ---------------------------------------------------------------------------
// D2: pure gather -- no LDS, no barriers, no sort.  16 lanes per row, each
// lane owns 4 output columns.  Edge list is per-row contiguous in rowslab;
// int4 broadcast loads grab 2 edges at a time, dual accumulators, fused ReLU.
// ---------------------------------------------------------------------------
__global__ __launch_bounds__(256) void gather_rows(const int* __restrict__ rowcnt,
                                                   const int2* __restrict__ rowslab,
                                                   const _Float16* __restrict__ support,
                                                   float* __restrict__ out) {
    const int tid = threadIdx.x;
    const int g   = tid & 15;
    const int lr  = tid >> 4;
    const int row = blockIdx.x * 16 + lr;          // 3125 * 16 == 50000 exactly
    const int cnt = min(rowcnt[row], ROW_CAP);
    const int2* rs = rowslab + ((size_t)row << 6);
    const _Float16* sp = support + g * 4;

    float4 a0 = make_float4(0.f, 0.f, 0.f, 0.f);
    float4 a1 = make_float4(0.f, 0.f, 0.f, 0.f);
    int j = 0;
    for (; j + 2 <= cnt; j += 2) {
        int4 ee = *(const int4*)&rs[j];            // 2 edges, 16B broadcast load
        float v0 = __int_as_float(ee.y);
        float v1 = __int_as_float(ee.w);
        h4 s0 = *(const h4*)&sp[(size_t)ee.x * OUT_DIM];
        h4 s1 = *(const h4*)&sp[(size_t)ee.z * OUT_DIM];
        a0.x += v0 * (float)s0[0]; a0.y += v0 * (float)s0[1];
        a0.z += v0 * (float)s0[2]; a0.w += v0 * (float)s0[3];
        a1.x += v1 * (float)s1[0]; a1.y += v1 * (float)s1[1];
        a1.z += v1 * (float)s1[2]; a1.w += v1 * (float)s1[3];
    }
    if (j < cnt) {
        int2 e0 = rs[j];
        float v0 = __int_as_float(e0.y);
        h4 s0 = *(const h4*)&sp[(size_t)e0.x * OUT_DIM];
        a0.x += v0 * (float)s0[0]; a0.y += v0 * (float)s0[1];
        a0.z += v0 * (float)s0[2]; a0.w += v0 * (float)s0[3];
    }
    float4 r;
    r.x = fmaxf(a0.x + a1.x, 0.f);
    r.y = fmaxf(a0.y + a1.y, 0.f);
    r.z = fmaxf(a0.z + a1.z, 0.f);
    r.w = fmaxf(a0.w + a1.w, 0.f);
    *(float4*)&out[(size_t)row * OUT_DIM + g * 4] = r;
}

extern "C" void kernel_launch(void* const* d_in, const int* in_sizes, int n_in,
                              void* d_out, int out_size, void* d_ws, size_t ws_size,
                              hipStream_t stream) {
    const float* x    = (const float*)d_in[0];
    const int*   erow = (const int*)  d_in[1];
    const int*   ecol = (const int*)  d_in[2];
    const float* ev   = (const float*)d_in[3];
    const float* w    = (const float*)d_in[4];
    float* out = (float*)d_out;

    // workspace layout (16B-aligned), total ~32.2 MB (ws is 256 MiB)
    char* ws = (char*)d_ws;
    _Float16* support = (_Float16*)ws;               //  6,400,000 B
    int*  rowcnt  = (int*)(ws + 6400000);            //    200,000 B
    int2* rowslab = (int2*)(ws + 6600000);           // 25,600,000 B (50000*64*8)

    hipMemsetAsync(rowcnt, 0, sizeof(int) * N_NODES, stream);

    fused_gemm_fill<<<FILL_BLOCKS + GEMM_BLOCKS, 256, 0, stream>>>(
        x, w, erow, ecol, ev, support, rowcnt, rowslab);

    gather_rows<<<N_NODES / 16, 256, 0, stream>>>(rowcnt, rowslab, support, out);
}

// Round 2
// 130.462 us; speedup vs baseline: 1.1300x; 1.1300x over previous
//
#include <hip/hip_runtime.h>

#define N_NODES 50000
#define N_EDGES 800000
#define IN_DIM 128
#define OUT_DIM 64

#define GROUP_SHIFT 6                 // 64 rows per group
#define GROUP_ROWS 64
#define N_GROUPS 782                  // ceil(50000/64)
#define CHUNK2 2048                   // edges per fill block
#define FILL_BLOCKS 391               // 391*2048 >= 800000
#define CELL_CAP 8                    // edges per (group,block) cell = one 64B line
#define SPILL_CAP 64                  // per-group overflow slab (expected ~0.6 used)
#define SLAB 1216                     // per-group total capacity (mean 1024, +6 sigma)

typedef _Float16 h2 __attribute__((ext_vector_type(2)));
typedef _Float16 h4 __attribute__((ext_vector_type(4)));
typedef _Float16 h8 __attribute__((ext_vector_type(8)));
typedef float    f4 __attribute__((ext_vector_type(4)));

#define LDK 136    // padded fp16 K-stride (multiple of 8 -> 16B-aligned b128 rows)

// ---------------------------------------------------------------------------
// D1 (fused): blocks [0,391) = fill role; blocks [391,1173) = MFMA fp16 GEMM
// per 64-row group (unchanged, proven).  Fill role: deterministic
// per-(group,block) cells -- each fill block owns slot column blockIdx, so
// binning needs only BLOCK-LOCAL LDS cursors.  Global atomics: ~500 spill
// edges chip-wide (was 280K claim atomics in the 124us version, 800K
// fetch-adds in the 147us version).  Single pass over erow/ecol/eval.
// ---------------------------------------------------------------------------
__global__ __launch_bounds__(256) void fused_gemm_fill(const float* __restrict__ x,
                                                       const float* __restrict__ w,
                                                       const int* __restrict__ erow,
                                                       const int* __restrict__ ecol,
                                                       const float* __restrict__ eval,
                                                       _Float16* __restrict__ support,
                                                       int* __restrict__ gspill,
                                                       unsigned char* __restrict__ cnt8,
                                                       int2* __restrict__ spill,
                                                       int2* __restrict__ bucket) {
    __shared__ char smem[GROUP_ROWS * LDK * 2 + OUT_DIM * LDK * 2];  // 34816 B
    const int tid = threadIdx.x;

    if (blockIdx.x >= FILL_BLOCKS) {
        // ---- GEMM role (blocks 391..1172, group = blockIdx-391) ----
        _Float16* xb = (_Float16*)smem;                          // [64][LDK]
        _Float16* wt = (_Float16*)(smem + GROUP_ROWS * LDK * 2); // [64][LDK], wt[n][k]

        // conflict-free wt staging (register transpose, fp16-pair stores)
        {
            const int n_s = tid >> 2;         // 0..63
            const int kp0 = tid & 3;
            #pragma unroll
            for (int it = 0; it < 16; ++it) {
                int kp = kp0 + (it << 2);     // k-pair index 0..63
                int k  = kp << 1;
                h2 hv = { (_Float16)w[(size_t)k * OUT_DIM + n_s],
                          (_Float16)w[(size_t)(k + 1) * OUT_DIM + n_s] };
                *(h2*)&wt[n_s * LDK + k] = hv;
            }
        }
        const int rowbase = (blockIdx.x - FILL_BLOCKS) * GROUP_ROWS;
        for (int i = tid; i < GROUP_ROWS * (IN_DIM / 4); i += 256) {
            int r  = i >> 5;
            int kq = i & 31;
            int row = rowbase + r;
            float4 v = (row < N_NODES)
                           ? *(const float4*)&x[(size_t)row * IN_DIM + kq * 4]
                           : make_float4(0.f, 0.f, 0.f, 0.f);
            h4 hv = { (_Float16)v.x, (_Float16)v.y, (_Float16)v.z, (_Float16)v.w };
            *(h4*)&xb[r * LDK + kq * 4] = hv;
        }
        __syncthreads();

        const int wave = tid >> 6;
        const int lane = tid & 63;
        const int mrow = lane & 15;
        const int quad = lane >> 4;
        const int m0   = wave * 16;

        f4 acc[4];
        #pragma unroll
        for (int t = 0; t < 4; ++t) acc[t] = (f4){0.f, 0.f, 0.f, 0.f};

        #pragma unroll
        for (int ks = 0; ks < 4; ++ks) {
            int kof = ks * 32 + quad * 8;
            h8 a = *(h8*)&xb[(m0 + mrow) * LDK + kof];
            #pragma unroll
            for (int t = 0; t < 4; ++t) {
                h8 b = *(h8*)&wt[(t * 16 + mrow) * LDK + kof];
                acc[t] = __builtin_amdgcn_mfma_f32_16x16x32_f16(a, b, acc[t], 0, 0, 0);
            }
        }

        #pragma unroll
        for (int t = 0; t < 4; ++t) {
            #pragma unroll
            for (int r = 0; r < 4; ++r) {
                int row = rowbase + m0 + quad * 4 + r;
                if (row < N_NODES)
                    support[(size_t)row * OUT_DIM + t * 16 + mrow] = (_Float16)acc[t][r];
            }
        }
    } else {
        // ---- fill role (blocks 0..390): atomic-claim-free cell binning ----
        int* lcnt = (int*)smem;                         // [N_GROUPS]
        for (int i = tid; i < N_GROUPS; i += 256) lcnt[i] = 0;
        __syncthreads();
        const int base  = blockIdx.x * CHUNK2;
        const int cbase = blockIdx.x;                   // our slot column
        #pragma unroll
        for (int i = 0; i < CHUNK2 / 256; ++i) {
            int e = base + tid + i * 256;
            if (e < N_EDGES) {
                int r = erow[e];
                int c = ecol[e];
                float v = eval[e];
                int g = r >> GROUP_SHIFT;
                int payload = ((r & (GROUP_ROWS - 1)) << 16) | c;   // col < 65536 ok
                int p = atomicAdd(&lcnt[g], 1);                     // LDS, block-local
                if (p < CELL_CAP) {
                    bucket[((size_t)g * FILL_BLOCKS + cbase) * CELL_CAP + p] =
                        make_int2(payload, __float_as_int(v));
                } else {
                    int sp = atomicAdd(&gspill[g], 1);              // rare (~500 total)
                    if (sp < SPILL_CAP)
                        spill[(size_t)g * SPILL_CAP + sp] =
                            make_int2(payload, __float_as_int(v));
                }
            }
        }
        __syncthreads();
        // coalesced 782B count record for this slot column
        for (int i = tid; i < N_GROUPS; i += 256)
            cnt8[(size_t)cbase * N_GROUPS + i] =
                (unsigned char)min(lcnt[i], CELL_CAP);
    }
}

// ---------------------------------------------------------------------------
// D2: one 1024-thread block per 64-row group.  Phase A: thread-per-cell
// compaction of the 391 cells (+spill) into ebuf off a single LDS cursor,
// folding the row histogram in.  Then: wave-0 scan, in-LDS counting sort,
// 16-lanes-per-row dual-accumulator gather, fused ReLU (proven round-0 code).
// ---------------------------------------------------------------------------
__global__ __launch_bounds__(1024) void reduce_group(const unsigned char* __restrict__ cnt8,
                                                     const int* __restrict__ gspill,
                                                     const int2* __restrict__ bucket,
                                                     const int2* __restrict__ spill,
                                                     const _Float16* __restrict__ support,
                                                     float* __restrict__ out) {
    __shared__ int2 ebuf[SLAB];
    __shared__ int2 ebuf2[SLAB];
    __shared__ int  rcnt[GROUP_ROWS];
    __shared__ int  rstart[GROUP_ROWS + 1];
    __shared__ int  rcur[GROUP_ROWS];
    __shared__ int  tot;
    const int grp = blockIdx.x;
    const int tid = threadIdx.x;

    if (tid < GROUP_ROWS) rcnt[tid] = 0;
    if (tid == 0) tot = 0;
    __syncthreads();

    // phase A: compact cells into ebuf + histogram
    if (tid < FILL_BLOCKS) {
        int k = cnt8[(size_t)tid * N_GROUPS + grp];
        if (k) {
            int p = atomicAdd(&tot, k);
            const int2* cell = &bucket[((size_t)grp * FILL_BLOCKS + tid) * CELL_CAP];
            #pragma unroll 4
            for (int j = 0; j < k; ++j) {
                int2 cv = cell[j];
                if (p + j < SLAB) ebuf[p + j] = cv;
                atomicAdd(&rcnt[cv.x >> 16], 1);
            }
        }
    } else if (tid < FILL_BLOCKS + SPILL_CAP) {
        int t  = tid - FILL_BLOCKS;
        int cs = min(gspill[grp], SPILL_CAP);
        if (t < cs) {
            int2 cv = spill[(size_t)grp * SPILL_CAP + t];
            int p = atomicAdd(&tot, 1);
            if (p < SLAB) ebuf[p] = cv;
            atomicAdd(&rcnt[cv.x >> 16], 1);
        }
    }
    __syncthreads();
    const int cnt = min(tot, SLAB);

    if (tid < GROUP_ROWS) {
        int v = rcnt[tid];
        int s = v;
        #pragma unroll
        for (int off = 1; off < 64; off <<= 1) {
            int t = __shfl_up(s, off, 64);
            if (tid >= off) s += t;
        }
        rstart[tid] = s - v;
        rcur[tid]   = s - v;
        if (tid == 63) rstart[64] = s;
    }
    __syncthreads();
    for (int j = tid; j < cnt; j += 1024) {
        int2 cv = ebuf[j];
        int rl = cv.x >> 16;
        int p  = atomicAdd(&rcur[rl], 1);
        if (p < SLAB) ebuf2[p] = cv;
    }
    __syncthreads();

    const int g  = tid & 15;
    const int lr = tid >> 4;
    const int row = grp * GROUP_ROWS + lr;
    const int jb = min(rstart[lr], SLAB);
    const int je = min(rstart[lr + 1], SLAB);
    float4 acc0 = make_float4(0.f, 0.f, 0.f, 0.f);
    float4 acc1 = make_float4(0.f, 0.f, 0.f, 0.f);
    int j = jb;
    for (; j + 1 < je; j += 2) {
        int2 cv0 = ebuf2[j];
        int2 cv1 = ebuf2[j + 1];
        float v0 = __int_as_float(cv0.y);
        float v1 = __int_as_float(cv1.y);
        h4 s0 = *(const h4*)&support[(size_t)(cv0.x & 0xFFFF) * OUT_DIM + g * 4];
        h4 s1 = *(const h4*)&support[(size_t)(cv1.x & 0xFFFF) * OUT_DIM + g * 4];
        acc0.x += v0 * (float)s0[0];
        acc0.y += v0 * (float)s0[1];
        acc0.z += v0 * (float)s0[2];
        acc0.w += v0 * (float)s0[3];
        acc1.x += v1 * (float)s1[0];
        acc1.y += v1 * (float)s1[1];
        acc1.z += v1 * (float)s1[2];
        acc1.w += v1 * (float)s1[3];
    }
    if (j < je) {
        int2 cv = ebuf2[j];
        float v = __int_as_float(cv.y);
        h4 sr = *(const h4*)&support[(size_t)(cv.x & 0xFFFF) * OUT_DIM + g * 4];
        acc0.x += v * (float)sr[0];
        acc0.y += v * (float)sr[1];
        acc0.z += v * (float)sr[2];
        acc0.w += v * (float)sr[3];
    }
    if (row < N_NODES) {
        float4 a;
        a.x = fmaxf(acc0.x + acc1.x, 0.f);
        a.y = fmaxf(acc0.y + acc1.y, 0.f);
        a.z = fmaxf(acc0.z + acc1.z, 0.f);
        a.w = fmaxf(acc0.w + acc1.w, 0.f);
        *(float4*)&out[(size_t)row * OUT_DIM + g * 4] = a;
    }
}

extern "C" void kernel_launch(void* const* d_in, const int* in_sizes, int n_in,
                              void* d_out, int out_size, void* d_ws, size_t ws_size,
                              hipStream_t stream) {
    const float* x    = (const float*)d_in[0];
    const int*   erow = (const int*)  d_in[1];
    const int*   ecol = (const int*)  d_in[2];
    const float* ev   = (const float*)d_in[3];
    const float* w    = (const float*)d_in[4];
    float* out = (float*)d_out;

    // workspace layout (16B-aligned), total ~26.7 MB (ws is 256 MiB)
    char* ws = (char*)d_ws;
    _Float16*      support = (_Float16*)ws;                 //  6,400,000 B
    int*           gspill  = (int*)(ws + 6400000);          //      3,128 B
    unsigned char* cnt8    = (unsigned char*)(ws + 6403200);//    305,762 B
    int2*          spill   = (int2*)(ws + 6709504);         //    400,384 B
    int2*          bucket  = (int2*)(ws + 7109888);         // 19,568,768 B

    hipMemsetAsync(gspill, 0, sizeof(int) * N_GROUPS, stream);

    fused_gemm_fill<<<FILL_BLOCKS + N_GROUPS, 256, 0, stream>>>(
        x, w, erow, ecol, ev, support, gspill, cnt8, spill, bucket);

    reduce_group<<<N_GROUPS, 1024, 0, stream>>>(cnt8, gspill, bucket, spill,
                                                support, out);
}

// Round 3
// 130.004 us; speedup vs baseline: 1.1340x; 1.0035x over previous
//
#include <hip/hip_runtime.h>

#define N_NODES 50000
#define N_EDGES 800000
#define IN_DIM 128
#define OUT_DIM 64

#define GROUP_SHIFT 6                 // 64 rows per group
#define GROUP_ROWS 64
#define N_GROUPS 782                  // ceil(50000/64)
#define CHUNK2 2048                   // edges per fill/count block
#define FILL_BLOCKS 391               // 391*2048 >= 800000
#define SLAB 1216                     // per-group slab capacity (mean 1024, +6 sigma)

typedef _Float16 h2 __attribute__((ext_vector_type(2)));
typedef _Float16 h4 __attribute__((ext_vector_type(4)));
typedef _Float16 h8 __attribute__((ext_vector_type(8)));
typedef float    f4 __attribute__((ext_vector_type(4)));

#define LDK 136    // padded fp16 K-stride (multiple of 8 -> 16B-aligned b128 rows)

// ---------------------------------------------------------------------------
// K1: exact per-(block,group) edge counts.  LDS histogram, coalesced u16 out.
// ---------------------------------------------------------------------------
__global__ __launch_bounds__(256) void count_edges(const int* __restrict__ erow,
                                                   unsigned short* __restrict__ cnt16) {
    __shared__ int lcnt[N_GROUPS];
    const int tid = threadIdx.x;
    for (int i = tid; i < N_GROUPS; i += 256) lcnt[i] = 0;
    __syncthreads();
    const int base = blockIdx.x * CHUNK2;
    #pragma unroll
    for (int i = 0; i < CHUNK2 / 256; ++i) {
        int e = base + tid + i * 256;
        if (e < N_EDGES) atomicAdd(&lcnt[erow[e] >> GROUP_SHIFT], 1);
    }
    __syncthreads();
    for (int i = tid; i < N_GROUPS; i += 256)
        cnt16[(size_t)blockIdx.x * N_GROUPS + i] = (unsigned short)lcnt[i];
}

// ---------------------------------------------------------------------------
// K2: per-group exclusive scan over the 391 block counts -> deterministic
// write bases rbase[b][g] and group totals gtot[g].  32 lanes per group,
// 8 groups per 256-thread block (98 blocks).  Replaces 280K global claim
// atomics with a 2us scan.
// ---------------------------------------------------------------------------
__global__ __launch_bounds__(256) void scan_bases(const unsigned short* __restrict__ cnt16,
                                                  unsigned short* __restrict__ rbase,
                                                  int* __restrict__ gtot) {
    const int sub = threadIdx.x >> 5;        // 0..7: group slot in block
    const int l   = threadIdx.x & 31;        // lane within 32-wide scan
    const int g   = blockIdx.x * 8 + sub;
    if (g >= N_GROUPS) return;
    const int b0 = l * 13;
    const int b1 = min(b0 + 13, FILL_BLOCKS);  // 32*13 = 416 >= 391
    int s = 0;
    for (int b = b0; b < b1; ++b) s += cnt16[(size_t)b * N_GROUPS + g];
    int incl = s;
    #pragma unroll
    for (int off = 1; off < 32; off <<= 1) {
        int t = __shfl_up(incl, off, 32);
        if (l >= off) incl += t;
    }
    int run = incl - s;                      // exclusive base for this lane's span
    for (int b = b0; b < b1; ++b) {
        rbase[(size_t)b * N_GROUPS + g] = (unsigned short)run;
        run += cnt16[(size_t)b * N_GROUPS + g];
    }
    if (l == 31) gtot[g] = incl;
}

// ---------------------------------------------------------------------------
// K3 (fused): blocks [0,391) = single-pass fill (no global atomics: base from
// rbase, local offset from block-local LDS cursor; dense slab writes are
// fire-and-forget scatter hidden under the gemm blocks); blocks [391,1173) =
// MFMA fp16 GEMM per 64-row group (unchanged, proven).
// ---------------------------------------------------------------------------
__global__ __launch_bounds__(256) void fused_gemm_fill(const float* __restrict__ x,
                                                       const float* __restrict__ w,
                                                       const int* __restrict__ erow,
                                                       const int* __restrict__ ecol,
                                                       const float* __restrict__ eval,
                                                       _Float16* __restrict__ support,
                                                       const unsigned short* __restrict__ rbase,
                                                       int2* __restrict__ bucket) {
    __shared__ char smem[GROUP_ROWS * LDK * 2 + OUT_DIM * LDK * 2];  // 34816 B
    const int tid = threadIdx.x;

    if (blockIdx.x >= FILL_BLOCKS) {
        // ---- GEMM role (blocks 391..1172, group = blockIdx-391) ----
        _Float16* xb = (_Float16*)smem;                          // [64][LDK]
        _Float16* wt = (_Float16*)(smem + GROUP_ROWS * LDK * 2); // [64][LDK], wt[n][k]

        // conflict-free wt staging (register transpose, fp16-pair stores)
        {
            const int n_s = tid >> 2;         // 0..63
            const int kp0 = tid & 3;
            #pragma unroll
            for (int it = 0; it < 16; ++it) {
                int kp = kp0 + (it << 2);     // k-pair index 0..63
                int k  = kp << 1;
                h2 hv = { (_Float16)w[(size_t)k * OUT_DIM + n_s],
                          (_Float16)w[(size_t)(k + 1) * OUT_DIM + n_s] };
                *(h2*)&wt[n_s * LDK + k] = hv;
            }
        }
        const int rowbase = (blockIdx.x - FILL_BLOCKS) * GROUP_ROWS;
        for (int i = tid; i < GROUP_ROWS * (IN_DIM / 4); i += 256) {
            int r  = i >> 5;
            int kq = i & 31;
            int row = rowbase + r;
            float4 v = (row < N_NODES)
                           ? *(const float4*)&x[(size_t)row * IN_DIM + kq * 4]
                           : make_float4(0.f, 0.f, 0.f, 0.f);
            h4 hv = { (_Float16)v.x, (_Float16)v.y, (_Float16)v.z, (_Float16)v.w };
            *(h4*)&xb[r * LDK + kq * 4] = hv;
        }
        __syncthreads();

        const int wave = tid >> 6;
        const int lane = tid & 63;
        const int mrow = lane & 15;
        const int quad = lane >> 4;
        const int m0   = wave * 16;

        f4 acc[4];
        #pragma unroll
        for (int t = 0; t < 4; ++t) acc[t] = (f4){0.f, 0.f, 0.f, 0.f};

        #pragma unroll
        for (int ks = 0; ks < 4; ++ks) {
            int kof = ks * 32 + quad * 8;
            h8 a = *(h8*)&xb[(m0 + mrow) * LDK + kof];
            #pragma unroll
            for (int t = 0; t < 4; ++t) {
                h8 b = *(h8*)&wt[(t * 16 + mrow) * LDK + kof];
                acc[t] = __builtin_amdgcn_mfma_f32_16x16x32_f16(a, b, acc[t], 0, 0, 0);
            }
        }

        #pragma unroll
        for (int t = 0; t < 4; ++t) {
            #pragma unroll
            for (int r = 0; r < 4; ++r) {
                int row = rowbase + m0 + quad * 4 + r;
                if (row < N_NODES)
                    support[(size_t)row * OUT_DIM + t * 16 + mrow] = (_Float16)acc[t][r];
            }
        }
    } else {
        // ---- fill role (blocks 0..390): single-pass deterministic scatter ----
        int* lcnt = (int*)smem;                         // [N_GROUPS] local cursors
        for (int i = tid; i < N_GROUPS; i += 256) lcnt[i] = 0;
        __syncthreads();
        const int b    = blockIdx.x;
        const int base = b * CHUNK2;
        #pragma unroll
        for (int i = 0; i < CHUNK2 / 256; ++i) {
            int e = base + tid + i * 256;
            if (e < N_EDGES) {
                int r = erow[e];
                int c = ecol[e];
                float v = eval[e];
                int g = r >> GROUP_SHIFT;
                int p = atomicAdd(&lcnt[g], 1);         // LDS, block-local
                int pos = (int)rbase[(size_t)b * N_GROUPS + g] + p;  // exact, no races
                if (pos < SLAB)                          // stat. impossible overflow guard
                    bucket[(size_t)g * SLAB + pos] =
                        make_int2(((r & (GROUP_ROWS - 1)) << 16) | c,
                                  __float_as_int(v));
            }
        }
    }
}

// ---------------------------------------------------------------------------
// K4: one 1024-thread block per 64-row group.  Slab -> LDS + histogram;
// wave-0 scan; in-LDS counting sort; 16-lanes-per-row gather unrolled x4
// (4 independent support loads in flight per thread); fused ReLU.
// ---------------------------------------------------------------------------
__global__ __launch_bounds__(1024) void reduce_group(const int* __restrict__ gtot,
                                                     const int2* __restrict__ bucket,
                                                     const _Float16* __restrict__ support,
                                                     float* __restrict__ out) {
    __shared__ int2 ebuf[SLAB];
    __shared__ int2 ebuf2[SLAB];
    __shared__ int  rcnt[GROUP_ROWS];
    __shared__ int  rstart[GROUP_ROWS + 1];
    __shared__ int  rcur[GROUP_ROWS];
    const int grp = blockIdx.x;
    const int cnt = min(gtot[grp], SLAB);
    const size_t sb = (size_t)grp * SLAB;
    const int tid = threadIdx.x;

    if (tid < GROUP_ROWS) rcnt[tid] = 0;
    __syncthreads();
    for (int j = tid; j < cnt; j += 1024) {
        int2 cv = bucket[sb + j];
        ebuf[j] = cv;
        atomicAdd(&rcnt[cv.x >> 16], 1);
    }
    __syncthreads();
    if (tid < GROUP_ROWS) {
        int v = rcnt[tid];
        int s = v;
        #pragma unroll
        for (int off = 1; off < 64; off <<= 1) {
            int t = __shfl_up(s, off, 64);
            if (tid >= off) s += t;
        }
        rstart[tid] = s - v;
        rcur[tid]   = s - v;
        if (tid == 63) rstart[64] = s;
    }
    __syncthreads();
    for (int j = tid; j < cnt; j += 1024) {
        int2 cv = ebuf[j];
        int rl = cv.x >> 16;
        int p  = atomicAdd(&rcur[rl], 1);
        ebuf2[p] = cv;
    }
    __syncthreads();

    const int g  = tid & 15;
    const int lr = tid >> 4;
    const int row = grp * GROUP_ROWS + lr;
    const int jb = rstart[lr];
    const int je = rstart[lr + 1];
    float4 A0 = make_float4(0.f, 0.f, 0.f, 0.f);
    float4 A1 = make_float4(0.f, 0.f, 0.f, 0.f);
    float4 A2 = make_float4(0.f, 0.f, 0.f, 0.f);
    float4 A3 = make_float4(0.f, 0.f, 0.f, 0.f);
    int j = jb;
    for (; j + 4 <= je; j += 4) {
        int2 c0 = ebuf2[j];
        int2 c1 = ebuf2[j + 1];
        int2 c2 = ebuf2[j + 2];
        int2 c3 = ebuf2[j + 3];
        h4 s0 = *(const h4*)&support[(size_t)(c0.x & 0xFFFF) * OUT_DIM + g * 4];
        h4 s1 = *(const h4*)&support[(size_t)(c1.x & 0xFFFF) * OUT_DIM + g * 4];
        h4 s2 = *(const h4*)&support[(size_t)(c2.x & 0xFFFF) * OUT_DIM + g * 4];
        h4 s3 = *(const h4*)&support[(size_t)(c3.x & 0xFFFF) * OUT_DIM + g * 4];
        float v0 = __int_as_float(c0.y);
        float v1 = __int_as_float(c1.y);
        float v2 = __int_as_float(c2.y);
        float v3 = __int_as_float(c3.y);
        A0.x += v0 * (float)s0[0]; A0.y += v0 * (float)s0[1];
        A0.z += v0 * (float)s0[2]; A0.w += v0 * (float)s0[3];
        A1.x += v1 * (float)s1[0]; A1.y += v1 * (float)s1[1];
        A1.z += v1 * (float)s1[2]; A1.w += v1 * (float)s1[3];
        A2.x += v2 * (float)s2[0]; A2.y += v2 * (float)s2[1];
        A2.z += v2 * (float)s2[2]; A2.w += v2 * (float)s2[3];
        A3.x += v3 * (float)s3[0]; A3.y += v3 * (float)s3[1];
        A3.z += v3 * (float)s3[2]; A3.w += v3 * (float)s3[3];
    }
    for (; j < je; ++j) {
        int2 cv = ebuf2[j];
        float v = __int_as_float(cv.y);
        h4 sr = *(const h4*)&support[(size_t)(cv.x & 0xFFFF) * OUT_DIM + g * 4];
        A0.x += v * (float)sr[0]; A0.y += v * (float)sr[1];
        A0.z += v * (float)sr[2]; A0.w += v * (float)sr[3];
    }
    if (row < N_NODES) {
        float4 a;
        a.x = fmaxf(A0.x + A1.x + A2.x + A3.x, 0.f);
        a.y = fmaxf(A0.y + A1.y + A2.y + A3.y, 0.f);
        a.z = fmaxf(A0.z + A1.z + A2.z + A3.z, 0.f);
        a.w = fmaxf(A0.w + A1.w + A2.w + A3.w, 0.f);
        *(float4*)&out[(size_t)row * OUT_DIM + g * 4] = a;
    }
}

extern "C" void kernel_launch(void* const* d_in, const int* in_sizes, int n_in,
                              void* d_out, int out_size, void* d_ws, size_t ws_size,
                              hipStream_t stream) {
    const float* x    = (const float*)d_in[0];
    const int*   erow = (const int*)  d_in[1];
    const int*   ecol = (const int*)  d_in[2];
    const float* ev   = (const float*)d_in[3];
    const float* w    = (const float*)d_in[4];
    float* out = (float*)d_out;

    // workspace layout (16B-aligned), total ~15.2 MB (ws is 256 MiB)
    char* ws = (char*)d_ws;
    _Float16*       support = (_Float16*)ws;                  //  6,400,000 B
    unsigned short* cnt16   = (unsigned short*)(ws + 6400000);//    611,584 B (391*782*2)
    unsigned short* rbase   = (unsigned short*)(ws + 7011584);//    611,584 B
    int*            gtot    = (int*)(ws + 7623168);           //      3,200 B
    int2*           bucket  = (int2*)(ws + 7626496);          //  7,607,296 B

    count_edges<<<FILL_BLOCKS, 256, 0, stream>>>(erow, cnt16);
    scan_bases<<<(N_GROUPS + 7) / 8, 256, 0, stream>>>(cnt16, rbase, gtot);
    fused_gemm_fill<<<FILL_BLOCKS + N_GROUPS, 256, 0, stream>>>(
        x, w, erow, ecol, ev, support, rbase, bucket);
    reduce_group<<<N_GROUPS, 1024, 0, stream>>>(gtot, bucket, support, out);
}